// Round 14
// baseline (275.683 us; speedup 1.0000x reference)
//
#include <hip/hip_runtime.h>
#include <math.h>

#define NB 16      // batch
#define NC 3       // obs channels
#define NN 3000    // nodes
#define NT 50      // time
#define NE 96000   // edges
#define NR 3       // relations
#define NS 500     // selected stocks
#define NF 43      // feature dim
#define NFP 44     // padded feature dim
#define NBF (NB*NFP)   // 704 = 11 * 64: transposed row length per node
#define NBKT (NR*NN)   // 9000 buckets keyed (rel, dst)
#define CAP 96     // fixed bucket capacity (mean 10.7; Poisson tail @96 ~ 0)

// ---------------- workspace layout (floats, then ints) ----------------
// x_t / h1_t: [node][b*44+f]  (704 floats per node); lg: [b][501] logits
#define XT_OFF   0
#define H1_OFF   (XT_OFF + NN*NBF)
#define LG_OFF   (H1_OFF + NN*NBF)
#define INT_BASE (LG_OFF + NB*(NS+1))
#define CNT_OFF  0
#define DONE_OFF NBKT
#define EBUF_OFF (NBKT + 4)   // +4 keeps ebuf 16B-aligned for int4 loads

// ---------------- fused front: temporal features (A/B split) + bucket fill ----------------
// blocks [0,750):    phase A: short conv (t-sliced over 4 waves)
// blocks [750,1500): phase B: mid conv (channel pipelined) + long max
// blocks [1500,1875): bucket fill (count + place, no scan)
// NOTE: __launch_bounds__(256,3) — (256,4) forces lower VGPR and SPILLS
// (R11: WRITE_SIZE 14.9->19.4 MB, FETCH 30->37 MB, total +10 us). Keep 3.
__global__ __launch_bounds__(256, 3) void k_front(
    const float* __restrict__ obs,
    const float* __restrict__ ws1, const float* __restrict__ bs1,
    const float* __restrict__ ws2, const float* __restrict__ bs2,
    const float* __restrict__ wm1, const float* __restrict__ bm1,
    const float* __restrict__ wm2, const float* __restrict__ bm2,
    float* __restrict__ x,
    const int* __restrict__ ei, const int* __restrict__ et,
    int* __restrict__ cnt, int* __restrict__ ebuf)
{
    __shared__ float sp[4][64][23];   // [wave][node][partial]
    int tid = threadIdx.x;

    if (blockIdx.x >= 1500) {
        // ---- bucket fill: 375 blocks x 256 = 96000 exact ----
        int e = (blockIdx.x - 1500) * 256 + tid;
        int bkt = et[e] * NN + ei[NE + e];
        int pos = atomicAdd(&cnt[bkt], 1);
        if (pos < CAP) ebuf[bkt * CAP + pos] = ei[e];  // src
        return;
    }

    int wave = __builtin_amdgcn_readfirstlane(tid >> 6);
    int lane = tid & 63;

    if (blockIdx.x < 750) {
        // ---- phase A: short conv, slice of 12 t's per wave ----
        int idx = blockIdx.x * 64 + lane;
        int b = idx / NN, n = idx - b * NN;
        float wS[3][14];
        int base = 12 * wave;
        #pragma unroll
        for (int c = 0; c < 3; ++c) {
            const float2* p2 = (const float2*)(obs + ((size_t)(b * NC + c) * NN + n) * NT + base);
            #pragma unroll
            for (int jj = 0; jj < 7; ++jj) {
                float2 u = p2[jj];
                wS[c][2 * jj] = u.x; wS[c][2 * jj + 1] = u.y;
            }
        }
        float acc[20];
        #pragma unroll
        for (int o = 0; o < 20; ++o) acc[o] = 0.f;
        #pragma unroll
        for (int j = 0; j < 12; ++j) {
            float y[3];
            #pragma unroll
            for (int c = 0; c < 3; ++c) {
                float s = bs1[c];
                #pragma unroll
                for (int i = 0; i < 3; ++i)
                    #pragma unroll
                    for (int k = 0; k < 3; ++k)
                        s = fmaf(wS[i][j + k], ws1[(c * 3 + i) * 3 + k], s);
                y[c] = fmaxf(s, 0.f);
            }
            int gt = base + j;   // wave-uniform -> scalar loads of ws2
            #pragma unroll
            for (int o = 0; o < 20; ++o) {
                float a = acc[o];
                #pragma unroll
                for (int c = 0; c < 3; ++c)
                    a = fmaf(y[c], ws2[(o * 3 + c) * 48 + gt], a);
                acc[o] = a;
            }
        }
        #pragma unroll
        for (int o = 0; o < 20; ++o) sp[wave][lane][o] = acc[o];
        __syncthreads();
        // reduce: 64 nodes x 20 outputs = 1280 = 5*256
        #pragma unroll
        for (int q = 0; q < 5; ++q) {
            int item = q * 256 + tid;
            int node = item / 20, o = item - node * 20;
            int g = blockIdx.x * 64 + node;
            int bb = g / NN, nn = g - bb * NN;
            float s = ((sp[0][node][o] + sp[1][node][o]) +
                       (sp[2][node][o] + sp[3][node][o])) + bs2[o];
            x[(size_t)nn * NBF + bb * NFP + o] = fmaxf(s, 0.f);
        }
        return;
    }

    // ---- phase B: mid conv (channel-pipelined) + long max ----
    {
        int idx = (blockIdx.x - 750) * 64 + lane;
        int b = idx / NN, n = idx - b * NN;
        int mbase = (wave < 3) ? 8 * wave : 24;
        int nld   = (wave < 3) ? 14 : 13;    // float2 count (window 28 / 26)
        const float* orow = obs + ((size_t)b * NC * NN + n) * NT + mbase;

        float s[3][8];
        #pragma unroll
        for (int c = 0; c < 3; ++c)
            #pragma unroll
            for (int t = 0; t < 8; ++t) s[c][t] = bm1[c];
        float cmax[3];
        float wA[28], wB[28];

        // static double-buffered channel pipeline: load(i+1) overlaps compute(i)
        #define LOADW(buf, ch)                                                  \
        {                                                                       \
            const float2* p2 = (const float2*)(orow + (size_t)(ch) * NN * NT);  \
            _Pragma("unroll")                                                   \
            for (int jj = 0; jj < 14; ++jj) {                                   \
                if (jj < nld) {                                                 \
                    float2 u = p2[jj];                                          \
                    buf[2 * jj] = u.x; buf[2 * jj + 1] = u.y;                   \
                } else { buf[2 * jj] = 0.f; buf[2 * jj + 1] = 0.f; }            \
            }                                                                   \
        }
        #define COMPW(buf, ii)                                                  \
        {                                                                       \
            float m = buf[0];                                                   \
            _Pragma("unroll")                                                   \
            for (int t = 1; t < 28; ++t) m = fmaxf(m, buf[t]);                  \
            cmax[ii] = m;                                                       \
            _Pragma("unroll")                                                   \
            for (int c = 0; c < 3; ++c)                                         \
                _Pragma("unroll")                                               \
                for (int t = 0; t < 8; ++t) {                                   \
                    float a = s[c][t];                                          \
                    _Pragma("unroll")                                           \
                    for (int k = 0; k < 21; ++k)                                \
                        a = fmaf(buf[t + k], wm1[(c * 3 + (ii)) * 21 + k], a);  \
                    s[c][t] = a;                                                \
                }                                                               \
        }

        LOADW(wA, 0)
        LOADW(wB, 1)
        COMPW(wA, 0)
        LOADW(wA, 2)
        COMPW(wB, 1)
        COMPW(wA, 2)
        #undef LOADW
        #undef COMPW

        float acc[20];
        #pragma unroll
        for (int o = 0; o < 20; ++o) acc[o] = 0.f;
        int cntM = (wave < 3) ? 8 : 6;
        #pragma unroll
        for (int j = 0; j < 8; ++j) {
            if (j < cntM) {
                float y0 = fmaxf(s[0][j], 0.f);
                float y1 = fmaxf(s[1][j], 0.f);
                float y2 = fmaxf(s[2][j], 0.f);
                int gt = mbase + j;   // wave-uniform -> scalar loads of wm2
                #pragma unroll
                for (int o = 0; o < 20; ++o) {
                    float a = acc[o];
                    a = fmaf(y0, wm2[(o * 3 + 0) * 30 + gt], a);
                    a = fmaf(y1, wm2[(o * 3 + 1) * 30 + gt], a);
                    a = fmaf(y2, wm2[(o * 3 + 2) * 30 + gt], a);
                    acc[o] = a;
                }
            }
        }
        #pragma unroll
        for (int o = 0; o < 20; ++o) sp[wave][lane][o] = acc[o];
        #pragma unroll
        for (int c = 0; c < 3; ++c) sp[wave][lane][20 + c] = cmax[c];
    }
    __syncthreads();
    // reduce mid + long: 64 nodes x 23 = 1472 items
    #pragma unroll
    for (int q = 0; q < 6; ++q) {
        int item = q * 256 + tid;
        if (item < 1472) {
            int node = item / 23, o = item - node * 23;
            int g = (blockIdx.x - 750) * 64 + node;
            int bb = g / NN, nn = g - bb * NN;
            size_t row = (size_t)nn * NBF + bb * NFP;
            if (o < 20) {
                float s = ((sp[0][node][o] + sp[1][node][o]) +
                           (sp[2][node][o] + sp[3][node][o])) + bm2[o];
                x[row + 20 + o] = fmaxf(s, 0.f);
            } else {
                float m = fmaxf(fmaxf(sp[0][node][o], sp[1][node][o]),
                                fmaxf(sp[2][node][o], sp[3][node][o]));
                x[row + 40 + (o - 20)] = fmaxf(m, 0.f);
            }
        }
    }
}

// ---------------- fused RGCN layer: block per dst, z stays in LDS ----------------
// Phase 1 (slab-split, balanced): wave w owns slabs {w, w+4, w+8} (w=3: {3,7}).
// Every wave walks ALL 3 buckets + self row for its slabs -> identical edge
// walks, zero inter-wave imbalance (R13's relation-split left wave 3 idle and
// stalled on the max bucket).
// Phase 2: k-split xform — wave w applies matrix w (0=root, 1..3=rel) to
// A-slabs read from LDS as float4 broadcasts; cross-wave reduce in sP.
// SEL=false: out = h1_t. SEL=true: logits -> lg, then the LAST block to finish
// (device-scope counter) computes the softmax and writes d_out directly.
template<bool LEAKY, bool SEL>
__global__ __launch_bounds__(256) void k_rgcn(
    const float* __restrict__ in, const float* __restrict__ xsrc,
    const int* __restrict__ cnt, const int* __restrict__ ebuf,
    const int* __restrict__ sel,
    const float* __restrict__ root, const float* __restrict__ rel,
    const float* __restrict__ bias,
    const float* __restrict__ la, const float* __restrict__ wf,
    const float* __restrict__ bf,
    float* __restrict__ out, int* __restrict__ done,
    float* __restrict__ res)
{
    __shared__ float lrow[4][NBF];    // self | z0 | z1 | z2  (11264 B)
    __shared__ float sP[8][4][NFP];   // partials (5632 B)
    __shared__ int slast;

    int tid = threadIdx.x;
    int wave = __builtin_amdgcn_readfirstlane(tid >> 6);
    int lane = tid & 63;
    int i = blockIdx.x;
    int node = __builtin_amdgcn_readfirstlane(SEL ? sel[i] : i);

    // weight column (VGPR-resident), loaded early to overlap phase-1 latency
    const float* wbase = (wave == 0) ? root : (rel + (size_t)(wave - 1) * NF * NF);
    float wsl[43];
    #pragma unroll
    for (int j = 0; j < 43; ++j)
        wsl[j] = (lane < NF) ? wbase[j * NF + lane] : 0.f;

    // ---- phase 1: slab-split aggregation ----
    int base = wave * 64 + lane;          // slab j = wave (+4, +8)
    bool has3 = (wave < 3);               // wave 3 has only slabs {3,7}

    #define ACT(v) (LEAKY ? ((v) >= 0.f ? (v) : 0.01f * (v)) : (v))
    {
        const float* p = in + (size_t)node * NBF;
        float v0 = p[base], v1 = p[base + 256];
        float v2 = has3 ? p[base + 512] : 0.f;
        lrow[0][base] = ACT(v0);
        lrow[0][base + 256] = ACT(v1);
        if (has3) lrow[0][base + 512] = ACT(v2);
    }
    #pragma unroll 1
    for (int r = 0; r < NR; ++r) {
        int bkt = r * NN + node;
        int cvr = __builtin_amdgcn_readfirstlane(cnt[bkt]);
        float ic = 1.0f / fmaxf((float)cvr, 1.0f);
        int cv = cvr > CAP ? CAP : cvr;
        const int* eb = ebuf + bkt * CAP;

        float a0 = 0.f, a1 = 0.f, a2 = 0.f;
        for (int e = 0; e < cv; e += 4) {
            int4 q = *(const int4*)(eb + e);   // 16B-aligned (CAP*4 = 384)
            int m = cv - e;
            {
                const float* p = in + (size_t)__builtin_amdgcn_readfirstlane(q.x) * NBF;
                float u0 = p[base], u1 = p[base + 256];
                a0 += ACT(u0); a1 += ACT(u1);
                if (has3) { float u2 = p[base + 512]; a2 += ACT(u2); }
            }
            if (m > 1) {
                const float* p = in + (size_t)__builtin_amdgcn_readfirstlane(q.y) * NBF;
                float u0 = p[base], u1 = p[base + 256];
                a0 += ACT(u0); a1 += ACT(u1);
                if (has3) { float u2 = p[base + 512]; a2 += ACT(u2); }
            }
            if (m > 2) {
                const float* p = in + (size_t)__builtin_amdgcn_readfirstlane(q.z) * NBF;
                float u0 = p[base], u1 = p[base + 256];
                a0 += ACT(u0); a1 += ACT(u1);
                if (has3) { float u2 = p[base + 512]; a2 += ACT(u2); }
            }
            if (m > 3) {
                const float* p = in + (size_t)__builtin_amdgcn_readfirstlane(q.w) * NBF;
                float u0 = p[base], u1 = p[base + 256];
                a0 += ACT(u0); a1 += ACT(u1);
                if (has3) { float u2 = p[base + 512]; a2 += ACT(u2); }
            }
        }
        lrow[r + 1][base] = a0 * ic;
        lrow[r + 1][base + 256] = a1 * ic;
        if (has3) lrow[r + 1][base + 512] = a2 * ic;
    }
    #undef ACT
    __syncthreads();

    // ---- phase 2: 16 batch-rows in 2 halves of 8 ----
    for (int h = 0; h < 2; ++h) {
        #pragma unroll
        for (int rr = 0; rr < 8; ++rr) {
            int b = h * 8 + rr;
            const float4* a4 = (const float4*)&lrow[wave][b * NFP];  // LDS broadcast
            float a0 = 0.f, a1 = 0.f, a2 = 0.f, a3 = 0.f;
            #pragma unroll
            for (int c = 0; c < 10; ++c) {
                float4 v = a4[c];
                a0 = fmaf(v.x, wsl[4 * c], a0);
                a1 = fmaf(v.y, wsl[4 * c + 1], a1);
                a2 = fmaf(v.z, wsl[4 * c + 2], a2);
                a3 = fmaf(v.w, wsl[4 * c + 3], a3);
            }
            {
                float4 v = a4[10];   // j = 40..43 (43 is pad, skipped)
                a0 = fmaf(v.x, wsl[40], a0);
                a1 = fmaf(v.y, wsl[41], a1);
                a2 = fmaf(v.z, wsl[42], a2);
            }
            if (lane < NF) sP[rr][wave][lane] = (a0 + a1) + (a2 + a3);
        }
        __syncthreads();

        // each wave reduces 2 rows
        int r0 = 2 * wave, r1 = 2 * wave + 1;
        int b0 = h * 8 + r0, b1 = h * 8 + r1;
        if (!SEL) {
            if (lane < NF) {
                float bi_ = bias[lane];
                float s0 = ((sP[r0][0][lane] + sP[r0][1][lane]) +
                            (sP[r0][2][lane] + sP[r0][3][lane])) + bi_;
                float s1 = ((sP[r1][0][lane] + sP[r1][1][lane]) +
                            (sP[r1][2][lane] + sP[r1][3][lane])) + bi_;
                out[(size_t)i * NBF + b0 * NFP + lane] = s0;
                out[(size_t)i * NBF + b1 * NFP + lane] = s1;
            }
        } else {
            // logits: lg[b] = bf + wf0*la + sum_f wf1[f]*x[f] + wf2[f]*leaky(h2[f])
            float p0 = 0.f, p1 = 0.f;
            if (lane < NF) {
                float bi_ = bias[lane];
                float s0 = ((sP[r0][0][lane] + sP[r0][1][lane]) +
                            (sP[r0][2][lane] + sP[r0][3][lane])) + bi_;
                float s1 = ((sP[r1][0][lane] + sP[r1][1][lane]) +
                            (sP[r1][2][lane] + sP[r1][3][lane])) + bi_;
                s0 = s0 >= 0.f ? s0 : 0.01f * s0;
                s1 = s1 >= 0.f ? s1 : 0.01f * s1;
                float x0 = xsrc[(size_t)node * NBF + b0 * NFP + lane];
                float x1 = xsrc[(size_t)node * NBF + b1 * NFP + lane];
                p0 = fmaf(wf[44 + lane], s0, wf[1 + lane] * x0);
                p1 = fmaf(wf[44 + lane], s1, wf[1 + lane] * x1);
            }
            #pragma unroll
            for (int o = 32; o > 0; o >>= 1) {
                p0 += __shfl_down(p0, o);
                p1 += __shfl_down(p1, o);
            }
            if (lane == 0) {
                out[(size_t)b0 * (NS + 1) + 1 + i] =
                    p0 + bf[0] + wf[0] * la[b0 * (NS + 1) + 1 + i];
                out[(size_t)b1 * (NS + 1) + 1 + i] =
                    p1 + bf[0] + wf[0] * la[b1 * (NS + 1) + 1 + i];
            }
        }
        __syncthreads();
    }

    // ---- SEL only: last block to finish computes the softmax ----
    if (SEL) {
        __threadfence();                       // publish this block's lg writes
        if (tid == 0) {
            int old = atomicAdd(done, 1);      // device-scope join
            slast = (old == NS - 1) ? 1 : 0;
        }
        __syncthreads();
        if (slast) {
            __threadfence();                   // see all other blocks' lg
            for (int bb = wave; bb < NB; bb += 4) {
                const float* l = out + (size_t)bb * (NS + 1);
                float vals[8]; float mx = -3.0e38f;
                #pragma unroll
                for (int k = 0; k < 8; ++k) {
                    int idx = k * 64 + lane;
                    float v = (idx == 0) ? 0.f
                            : ((idx <= NS) ? l[idx] : -3.0e38f);
                    vals[k] = v; mx = fmaxf(mx, v);
                }
                #pragma unroll
                for (int o = 32; o > 0; o >>= 1) mx = fmaxf(mx, __shfl_xor(mx, o));
                float ev[8]; float se = 0.f;
                #pragma unroll
                for (int k = 0; k < 8; ++k) {
                    int idx = k * 64 + lane;
                    float e = (idx <= NS) ? expf(vals[k] - mx) : 0.f;
                    ev[k] = e; se += e;
                }
                #pragma unroll
                for (int o = 32; o > 0; o >>= 1) se += __shfl_xor(se, o);
                float inv = 1.f / se;
                #pragma unroll
                for (int k = 0; k < 8; ++k) {
                    int idx = k * 64 + lane;
                    if (idx <= NS) res[(size_t)bb * (NS + 1) + idx] = ev[k] * inv;
                }
            }
        }
    }
}

extern "C" void kernel_launch(void* const* d_in, const int* in_sizes, int n_in,
                              void* d_out, int out_size, void* d_ws, size_t ws_size,
                              hipStream_t stream)
{
    const float* obs   = (const float*)d_in[0];
    const float* la    = (const float*)d_in[1];
    const int*   ei    = (const int*)d_in[2];
    const int*   et    = (const int*)d_in[3];
    const int*   nodes = (const int*)d_in[4];
    const float* ws1 = (const float*)d_in[5],  *bs1 = (const float*)d_in[6];
    const float* ws2 = (const float*)d_in[7],  *bs2 = (const float*)d_in[8];
    const float* wm1 = (const float*)d_in[9],  *bm1 = (const float*)d_in[10];
    const float* wm2 = (const float*)d_in[11], *bm2 = (const float*)d_in[12];
    const float* root1 = (const float*)d_in[13], *rel1 = (const float*)d_in[14], *bias1 = (const float*)d_in[15];
    const float* root2 = (const float*)d_in[16], *rel2 = (const float*)d_in[17], *bias2 = (const float*)d_in[18];
    const float* wf = (const float*)d_in[19], *bf = (const float*)d_in[20];

    float* wsp = (float*)d_ws;
    float* x   = wsp + XT_OFF;
    float* h1  = wsp + H1_OFF;
    float* lg  = wsp + LG_OFF;
    int*   ibase = (int*)(wsp + INT_BASE);
    int*   cnt   = ibase + CNT_OFF;
    int*   done  = ibase + DONE_OFF;
    int*   ebuf  = ibase + EBUF_OFF;

    // zero cnt + done counter (contiguous)
    hipMemsetAsync(cnt, 0, (NBKT + 4) * sizeof(int), stream);

    // fused: phase A (0..749) + phase B (750..1499) + bucket fill (1500..1874)
    k_front<<<1875, 256, 0, stream>>>(
        obs, ws1, bs1, ws2, bs2, wm1, bm1, wm2, bm2, x, ei, et, cnt, ebuf);

    // RGCN layer 1 fused (agg + xform, z in LDS): block per node
    k_rgcn<false, false><<<NN, 256, 0, stream>>>(
        x, nullptr, cnt, ebuf, nullptr, root1, rel1, bias1,
        nullptr, nullptr, nullptr, h1, done, nullptr);

    // RGCN layer 2 fused (agg + xform + logits + last-block softmax)
    k_rgcn<true, true><<<NS, 256, 0, stream>>>(
        h1, x, cnt, ebuf, nodes, root2, rel2, bias2,
        la, wf, bf, lg, done, (float*)d_out);
}

// Round 15
// 209.165 us; speedup vs baseline: 1.3180x; 1.3180x over previous
//
#include <hip/hip_runtime.h>
#include <math.h>

#define NB 16      // batch
#define NC 3       // obs channels
#define NN 3000    // nodes
#define NT 50      // time
#define NE 96000   // edges
#define NR 3       // relations
#define NS 500     // selected stocks
#define NF 43      // feature dim
#define NFP 44     // padded feature dim
#define NBF (NB*NFP)   // 704 = 11 * 64: transposed row length per node
#define NBKT (NR*NN)   // 9000 buckets keyed (rel, dst)
#define CAP 96     // fixed bucket capacity (mean 10.7; Poisson tail @96 ~ 0)

// ---------------- workspace layout (floats, then ints) ----------------
// x_t / h1_t: [node][b*44+f]  (704 floats per node); lg: [b][501] logits
#define XT_OFF   0
#define H1_OFF   (XT_OFF + NN*NBF)
#define LG_OFF   (H1_OFF + NN*NBF)
#define INT_BASE (LG_OFF + NB*(NS+1))
#define CNT_OFF  0
#define EBUF_OFF (CNT_OFF + NBKT)

// ---------------- fused front: temporal features (A/B split) + bucket fill ----------------
// blocks [0,750):    phase A: short conv (t-sliced over 4 waves)
// blocks [750,1500): phase B: mid conv (channel pipelined) + long max
// blocks [1500,1875): bucket fill (count + place, no scan)
// NOTE: __launch_bounds__(256,3) — (256,4) forces lower VGPR and SPILLS
// (R11: WRITE_SIZE 14.9->19.4 MB, FETCH 30->37 MB, total +10 us). Keep 3.
__global__ __launch_bounds__(256, 3) void k_front(
    const float* __restrict__ obs,
    const float* __restrict__ ws1, const float* __restrict__ bs1,
    const float* __restrict__ ws2, const float* __restrict__ bs2,
    const float* __restrict__ wm1, const float* __restrict__ bm1,
    const float* __restrict__ wm2, const float* __restrict__ bm2,
    float* __restrict__ x,
    const int* __restrict__ ei, const int* __restrict__ et,
    int* __restrict__ cnt, int* __restrict__ ebuf)
{
    __shared__ float sp[4][64][23];   // [wave][node][partial]
    int tid = threadIdx.x;

    if (blockIdx.x >= 1500) {
        // ---- bucket fill: 375 blocks x 256 = 96000 exact ----
        int e = (blockIdx.x - 1500) * 256 + tid;
        int bkt = et[e] * NN + ei[NE + e];
        int pos = atomicAdd(&cnt[bkt], 1);
        if (pos < CAP) ebuf[bkt * CAP + pos] = ei[e];  // src
        return;
    }

    int wave = __builtin_amdgcn_readfirstlane(tid >> 6);
    int lane = tid & 63;

    if (blockIdx.x < 750) {
        // ---- phase A: short conv, slice of 12 t's per wave ----
        int idx = blockIdx.x * 64 + lane;
        int b = idx / NN, n = idx - b * NN;
        float wS[3][14];
        int base = 12 * wave;
        #pragma unroll
        for (int c = 0; c < 3; ++c) {
            const float2* p2 = (const float2*)(obs + ((size_t)(b * NC + c) * NN + n) * NT + base);
            #pragma unroll
            for (int jj = 0; jj < 7; ++jj) {
                float2 u = p2[jj];
                wS[c][2 * jj] = u.x; wS[c][2 * jj + 1] = u.y;
            }
        }
        float acc[20];
        #pragma unroll
        for (int o = 0; o < 20; ++o) acc[o] = 0.f;
        #pragma unroll
        for (int j = 0; j < 12; ++j) {
            float y[3];
            #pragma unroll
            for (int c = 0; c < 3; ++c) {
                float s = bs1[c];
                #pragma unroll
                for (int i = 0; i < 3; ++i)
                    #pragma unroll
                    for (int k = 0; k < 3; ++k)
                        s = fmaf(wS[i][j + k], ws1[(c * 3 + i) * 3 + k], s);
                y[c] = fmaxf(s, 0.f);
            }
            int gt = base + j;   // wave-uniform -> scalar loads of ws2
            #pragma unroll
            for (int o = 0; o < 20; ++o) {
                float a = acc[o];
                #pragma unroll
                for (int c = 0; c < 3; ++c)
                    a = fmaf(y[c], ws2[(o * 3 + c) * 48 + gt], a);
                acc[o] = a;
            }
        }
        #pragma unroll
        for (int o = 0; o < 20; ++o) sp[wave][lane][o] = acc[o];
        __syncthreads();
        // reduce: 64 nodes x 20 outputs = 1280 = 5*256
        #pragma unroll
        for (int q = 0; q < 5; ++q) {
            int item = q * 256 + tid;
            int node = item / 20, o = item - node * 20;
            int g = blockIdx.x * 64 + node;
            int bb = g / NN, nn = g - bb * NN;
            float s = ((sp[0][node][o] + sp[1][node][o]) +
                       (sp[2][node][o] + sp[3][node][o])) + bs2[o];
            x[(size_t)nn * NBF + bb * NFP + o] = fmaxf(s, 0.f);
        }
        return;
    }

    // ---- phase B: mid conv (channel-pipelined) + long max ----
    {
        int idx = (blockIdx.x - 750) * 64 + lane;
        int b = idx / NN, n = idx - b * NN;
        int mbase = (wave < 3) ? 8 * wave : 24;
        int nld   = (wave < 3) ? 14 : 13;    // float2 count (window 28 / 26)
        const float* orow = obs + ((size_t)b * NC * NN + n) * NT + mbase;

        float s[3][8];
        #pragma unroll
        for (int c = 0; c < 3; ++c)
            #pragma unroll
            for (int t = 0; t < 8; ++t) s[c][t] = bm1[c];
        float cmax[3];
        float wA[28], wB[28];

        // static double-buffered channel pipeline: load(i+1) overlaps compute(i)
        #define LOADW(buf, ch)                                                  \
        {                                                                       \
            const float2* p2 = (const float2*)(orow + (size_t)(ch) * NN * NT);  \
            _Pragma("unroll")                                                   \
            for (int jj = 0; jj < 14; ++jj) {                                   \
                if (jj < nld) {                                                 \
                    float2 u = p2[jj];                                          \
                    buf[2 * jj] = u.x; buf[2 * jj + 1] = u.y;                   \
                } else { buf[2 * jj] = 0.f; buf[2 * jj + 1] = 0.f; }            \
            }                                                                   \
        }
        #define COMPW(buf, ii)                                                  \
        {                                                                       \
            float m = buf[0];                                                   \
            _Pragma("unroll")                                                   \
            for (int t = 1; t < 28; ++t) m = fmaxf(m, buf[t]);                  \
            cmax[ii] = m;                                                       \
            _Pragma("unroll")                                                   \
            for (int c = 0; c < 3; ++c)                                         \
                _Pragma("unroll")                                               \
                for (int t = 0; t < 8; ++t) {                                   \
                    float a = s[c][t];                                          \
                    _Pragma("unroll")                                           \
                    for (int k = 0; k < 21; ++k)                                \
                        a = fmaf(buf[t + k], wm1[(c * 3 + (ii)) * 21 + k], a);  \
                    s[c][t] = a;                                                \
                }                                                               \
        }

        LOADW(wA, 0)
        LOADW(wB, 1)
        COMPW(wA, 0)
        LOADW(wA, 2)
        COMPW(wB, 1)
        COMPW(wA, 2)
        #undef LOADW
        #undef COMPW

        float acc[20];
        #pragma unroll
        for (int o = 0; o < 20; ++o) acc[o] = 0.f;
        int cntM = (wave < 3) ? 8 : 6;
        #pragma unroll
        for (int j = 0; j < 8; ++j) {
            if (j < cntM) {
                float y0 = fmaxf(s[0][j], 0.f);
                float y1 = fmaxf(s[1][j], 0.f);
                float y2 = fmaxf(s[2][j], 0.f);
                int gt = mbase + j;   // wave-uniform -> scalar loads of wm2
                #pragma unroll
                for (int o = 0; o < 20; ++o) {
                    float a = acc[o];
                    a = fmaf(y0, wm2[(o * 3 + 0) * 30 + gt], a);
                    a = fmaf(y1, wm2[(o * 3 + 1) * 30 + gt], a);
                    a = fmaf(y2, wm2[(o * 3 + 2) * 30 + gt], a);
                    acc[o] = a;
                }
            }
        }
        #pragma unroll
        for (int o = 0; o < 20; ++o) sp[wave][lane][o] = acc[o];
        #pragma unroll
        for (int c = 0; c < 3; ++c) sp[wave][lane][20 + c] = cmax[c];
    }
    __syncthreads();
    // reduce mid + long: 64 nodes x 23 = 1472 items
    #pragma unroll
    for (int q = 0; q < 6; ++q) {
        int item = q * 256 + tid;
        if (item < 1472) {
            int node = item / 23, o = item - node * 23;
            int g = (blockIdx.x - 750) * 64 + node;
            int bb = g / NN, nn = g - bb * NN;
            size_t row = (size_t)nn * NBF + bb * NFP;
            if (o < 20) {
                float s = ((sp[0][node][o] + sp[1][node][o]) +
                           (sp[2][node][o] + sp[3][node][o])) + bm2[o];
                x[row + 20 + o] = fmaxf(s, 0.f);
            } else {
                float m = fmaxf(fmaxf(sp[0][node][o], sp[1][node][o]),
                                fmaxf(sp[2][node][o], sp[3][node][o]));
                x[row + 40 + (o - 20)] = fmaxf(m, 0.f);
            }
        }
    }
}

// ---------------- fused RGCN layer: block per dst, z stays in LDS ----------------
// Phase 1: waves 0-2 aggregate bucket (r=wave, dst) for all 16 batches into
//          lrow[wave+1]; wave 3 loads the self row into lrow[0].
// Phase 2: k-split xform — wave w applies matrix w (0=root, 1..3=rel) to
//          A-slabs read from LDS as float4 broadcasts; cross-wave reduce in sP.
// SEL=false: out = h1_t [node][b*44+f].
// SEL=true:  logits computed in-register (h2 never materialized) -> out = lg.
// NOTE (R14): do NOT fuse softmax via device-scope last-block join — the
// __threadfence() pattern took L2 k_rgcn 15->70 us. Keep separate k_softmax.
template<bool LEAKY, bool SEL>
__global__ __launch_bounds__(256) void k_rgcn(
    const float* __restrict__ in, const float* __restrict__ xsrc,
    const int* __restrict__ cnt, const int* __restrict__ ebuf,
    const int* __restrict__ sel,
    const float* __restrict__ root, const float* __restrict__ rel,
    const float* __restrict__ bias,
    const float* __restrict__ la, const float* __restrict__ wf,
    const float* __restrict__ bf,
    float* __restrict__ out)
{
    __shared__ float lrow[4][NBF];    // self | z0 | z1 | z2  (11264 B)
    __shared__ float sP[8][4][NFP];   // partials (5632 B)

    int tid = threadIdx.x;
    int wave = __builtin_amdgcn_readfirstlane(tid >> 6);
    int lane = tid & 63;
    int i = blockIdx.x;
    int node = __builtin_amdgcn_readfirstlane(SEL ? sel[i] : i);

    // weight column (VGPR-resident), loaded early to overlap phase-1 latency
    const float* wbase = (wave == 0) ? root : (rel + (size_t)(wave - 1) * NF * NF);
    float wsl[43];
    #pragma unroll
    for (int j = 0; j < 43; ++j)
        wsl[j] = (lane < NF) ? wbase[j * NF + lane] : 0.f;

    // ---- phase 1 ----
    if (wave == 3) {
        #pragma unroll
        for (int j = 0; j < 11; ++j) {
            float v = in[(size_t)node * NBF + j * 64 + lane];
            if (LEAKY) v = v >= 0.f ? v : 0.01f * v;
            lrow[0][j * 64 + lane] = v;
        }
    } else {
        int bkt = wave * NN + node;
        int cvr = __builtin_amdgcn_readfirstlane(cnt[bkt]);
        float ic = 1.0f / fmaxf((float)cvr, 1.0f);
        int cv = cvr > CAP ? CAP : cvr;
        const int* eb = ebuf + bkt * CAP;

        float acc[11];
        #pragma unroll
        for (int j = 0; j < 11; ++j) acc[j] = 0.f;

        for (int e = 0; e < cv; e += 4) {
            int4 q = *(const int4*)(eb + e);   // 16B-aligned (CAP*4 = 384)
            int m = cv - e;
            {
                const float* p = in + (size_t)__builtin_amdgcn_readfirstlane(q.x) * NBF;
                #pragma unroll
                for (int j = 0; j < 11; ++j) {
                    float v = p[j * 64 + lane];
                    if (LEAKY) v = v >= 0.f ? v : 0.01f * v;
                    acc[j] += v;
                }
            }
            if (m > 1) {
                const float* p = in + (size_t)__builtin_amdgcn_readfirstlane(q.y) * NBF;
                #pragma unroll
                for (int j = 0; j < 11; ++j) {
                    float v = p[j * 64 + lane];
                    if (LEAKY) v = v >= 0.f ? v : 0.01f * v;
                    acc[j] += v;
                }
            }
            if (m > 2) {
                const float* p = in + (size_t)__builtin_amdgcn_readfirstlane(q.z) * NBF;
                #pragma unroll
                for (int j = 0; j < 11; ++j) {
                    float v = p[j * 64 + lane];
                    if (LEAKY) v = v >= 0.f ? v : 0.01f * v;
                    acc[j] += v;
                }
            }
            if (m > 3) {
                const float* p = in + (size_t)__builtin_amdgcn_readfirstlane(q.w) * NBF;
                #pragma unroll
                for (int j = 0; j < 11; ++j) {
                    float v = p[j * 64 + lane];
                    if (LEAKY) v = v >= 0.f ? v : 0.01f * v;
                    acc[j] += v;
                }
            }
        }
        #pragma unroll
        for (int j = 0; j < 11; ++j) lrow[wave + 1][j * 64 + lane] = acc[j] * ic;
    }
    __syncthreads();

    // ---- phase 2: 16 batch-rows in 2 halves of 8 ----
    for (int h = 0; h < 2; ++h) {
        #pragma unroll
        for (int rr = 0; rr < 8; ++rr) {
            int b = h * 8 + rr;
            const float4* a4 = (const float4*)&lrow[wave][b * NFP];  // LDS broadcast
            float a0 = 0.f, a1 = 0.f, a2 = 0.f, a3 = 0.f;
            #pragma unroll
            for (int c = 0; c < 10; ++c) {
                float4 v = a4[c];
                a0 = fmaf(v.x, wsl[4 * c], a0);
                a1 = fmaf(v.y, wsl[4 * c + 1], a1);
                a2 = fmaf(v.z, wsl[4 * c + 2], a2);
                a3 = fmaf(v.w, wsl[4 * c + 3], a3);
            }
            {
                float4 v = a4[10];   // j = 40..43 (43 is pad, skipped)
                a0 = fmaf(v.x, wsl[40], a0);
                a1 = fmaf(v.y, wsl[41], a1);
                a2 = fmaf(v.z, wsl[42], a2);
            }
            if (lane < NF) sP[rr][wave][lane] = (a0 + a1) + (a2 + a3);
        }
        __syncthreads();

        // each wave reduces 2 rows
        int r0 = 2 * wave, r1 = 2 * wave + 1;
        int b0 = h * 8 + r0, b1 = h * 8 + r1;
        if (!SEL) {
            if (lane < NF) {
                float bi_ = bias[lane];
                float s0 = ((sP[r0][0][lane] + sP[r0][1][lane]) +
                            (sP[r0][2][lane] + sP[r0][3][lane])) + bi_;
                float s1 = ((sP[r1][0][lane] + sP[r1][1][lane]) +
                            (sP[r1][2][lane] + sP[r1][3][lane])) + bi_;
                out[(size_t)i * NBF + b0 * NFP + lane] = s0;
                out[(size_t)i * NBF + b1 * NFP + lane] = s1;
            }
        } else {
            // logits: lg[b] = bf + wf0*la + sum_f wf1[f]*x[f] + wf2[f]*leaky(h2[f])
            float p0 = 0.f, p1 = 0.f;
            if (lane < NF) {
                float bi_ = bias[lane];
                float s0 = ((sP[r0][0][lane] + sP[r0][1][lane]) +
                            (sP[r0][2][lane] + sP[r0][3][lane])) + bi_;
                float s1 = ((sP[r1][0][lane] + sP[r1][1][lane]) +
                            (sP[r1][2][lane] + sP[r1][3][lane])) + bi_;
                s0 = s0 >= 0.f ? s0 : 0.01f * s0;
                s1 = s1 >= 0.f ? s1 : 0.01f * s1;
                float x0 = xsrc[(size_t)node * NBF + b0 * NFP + lane];
                float x1 = xsrc[(size_t)node * NBF + b1 * NFP + lane];
                p0 = fmaf(wf[44 + lane], s0, wf[1 + lane] * x0);
                p1 = fmaf(wf[44 + lane], s1, wf[1 + lane] * x1);
            }
            #pragma unroll
            for (int o = 32; o > 0; o >>= 1) {
                p0 += __shfl_down(p0, o);
                p1 += __shfl_down(p1, o);
            }
            if (lane == 0) {
                out[(size_t)b0 * (NS + 1) + 1 + i] =
                    p0 + bf[0] + wf[0] * la[b0 * (NS + 1) + 1 + i];
                out[(size_t)b1 * (NS + 1) + 1 + i] =
                    p1 + bf[0] + wf[0] * la[b1 * (NS + 1) + 1 + i];
            }
        }
        __syncthreads();
    }
}

// ---------------- softmax over 501 logits per batch ----------------
__device__ inline float wred_max(float v) {
    #pragma unroll
    for (int o = 32; o > 0; o >>= 1) v = fmaxf(v, __shfl_down(v, o));
    return v;
}
__device__ inline float wred_sum(float v) {
    #pragma unroll
    for (int o = 32; o > 0; o >>= 1) v += __shfl_down(v, o);
    return v;
}

__global__ __launch_bounds__(512) void k_softmax(
    const float* __restrict__ lg, float* __restrict__ out)
{
    __shared__ float sred[8];
    __shared__ float sbc[2];
    int b = blockIdx.x, tid = threadIdx.x;

    float val = -3.0e38f;
    if (tid <= NS) val = (tid == 0) ? 0.f : lg[(size_t)b * (NS + 1) + tid];

    float m = wred_max(val);
    if ((tid & 63) == 0) sred[tid >> 6] = m;
    __syncthreads();
    if (tid == 0) {
        float mm = sred[0];
        #pragma unroll
        for (int i = 1; i < 8; ++i) mm = fmaxf(mm, sred[i]);
        sbc[0] = mm;
    }
    __syncthreads();
    float mx = sbc[0];
    float e = (tid <= NS) ? expf(val - mx) : 0.f;
    float s = wred_sum(e);
    if ((tid & 63) == 0) sred[tid >> 6] = s;
    __syncthreads();
    if (tid == 0) {
        float t = 0.f;
        #pragma unroll
        for (int i = 0; i < 8; ++i) t += sred[i];
        sbc[1] = t;
    }
    __syncthreads();
    if (tid <= NS) out[(size_t)b * (NS + 1) + tid] = e / sbc[1];
}

extern "C" void kernel_launch(void* const* d_in, const int* in_sizes, int n_in,
                              void* d_out, int out_size, void* d_ws, size_t ws_size,
                              hipStream_t stream)
{
    const float* obs   = (const float*)d_in[0];
    const float* la    = (const float*)d_in[1];
    const int*   ei    = (const int*)d_in[2];
    const int*   et    = (const int*)d_in[3];
    const int*   nodes = (const int*)d_in[4];
    const float* ws1 = (const float*)d_in[5],  *bs1 = (const float*)d_in[6];
    const float* ws2 = (const float*)d_in[7],  *bs2 = (const float*)d_in[8];
    const float* wm1 = (const float*)d_in[9],  *bm1 = (const float*)d_in[10];
    const float* wm2 = (const float*)d_in[11], *bm2 = (const float*)d_in[12];
    const float* root1 = (const float*)d_in[13], *rel1 = (const float*)d_in[14], *bias1 = (const float*)d_in[15];
    const float* root2 = (const float*)d_in[16], *rel2 = (const float*)d_in[17], *bias2 = (const float*)d_in[18];
    const float* wf = (const float*)d_in[19], *bf = (const float*)d_in[20];

    float* wsp = (float*)d_ws;
    float* x   = wsp + XT_OFF;
    float* h1  = wsp + H1_OFF;
    float* lg  = wsp + LG_OFF;
    int*   ibase = (int*)(wsp + INT_BASE);
    int*   cnt   = ibase + CNT_OFF;
    int*   ebuf  = ibase + EBUF_OFF;

    hipMemsetAsync(cnt, 0, NBKT * sizeof(int), stream);

    // fused: phase A (0..749) + phase B (750..1499) + bucket fill (1500..1874)
    k_front<<<1875, 256, 0, stream>>>(
        obs, ws1, bs1, ws2, bs2, wm1, bm1, wm2, bm2, x, ei, et, cnt, ebuf);

    // RGCN layer 1 fused (agg + xform, z in LDS): block per node
    k_rgcn<false, false><<<NN, 256, 0, stream>>>(
        x, nullptr, cnt, ebuf, nullptr, root1, rel1, bias1,
        nullptr, nullptr, nullptr, h1);

    // RGCN layer 2 fused (agg + xform + logits): block per selected stock
    k_rgcn<true, true><<<NS, 256, 0, stream>>>(
        h1, x, cnt, ebuf, nodes, root2, rel2, bias2,
        la, wf, bf, lg);

    k_softmax<<<NB, 512, 0, stream>>>(lg, (float*)d_out);
}